// Round 11
// baseline (199.735 us; speedup 1.0000x reference)
//
#include <hip/hip_runtime.h>
#include <hip/hip_bf16.h>
#include <cmath>

// Problem constants
#define B_SZ 8
#define L_SZ 2048
#define D_SZ 1024
#define CH 341
#define CP 384               // padded channel dim (24 x 16)
#define LCONV 2046           // L - KERNEL + 1
#define NSEG 512
#define KDIM 3072            // 3 * 1024 folded conv K
#define KSTEPS 48            // KDIM / 64
#define NCHUNK 128           // 16-token chunks per batch
#define W1XB 576             // w1-pack x-blocks per batch slice (576*8*256 = 384*3072)

#define POOLED_N (B_SZ * NSEG * D_SZ)

typedef _Float16 f16x8 __attribute__((ext_vector_type(8)));
typedef _Float16 f16x4 __attribute__((ext_vector_type(4)));
typedef float f32x4 __attribute__((ext_vector_type(4)));

__device__ __forceinline__ void gl_lds16(const void* g, void* l) {
    __builtin_amdgcn_global_load_lds(
        (const __attribute__((address_space(1))) unsigned int*)g,
        (__attribute__((address_space(3))) unsigned int*)l, 16, 0, 0);
}

// ---------------------------------------------------------------------------
// Fused converts + chunk sums:
// blocks x<NCHUNK (per b): convert 16 hidden rows fp32->fp16 AND accumulate
//   the chunk row-sum (boundary-independent pooling partial; zero extra
//   global traffic beyond the 4 MB chunksum write).
// blocks x>=NCHUNK: w1 -> bfrag fragment-pack + logits init to b2.
// bfrag layout (EXACT MFMA B-fragment order):
//   flat f16 index fo = (((tt*48 + s)*2 + kc)*64 + lane)*8 + j
//   content: channel c = tt*16 + (lane&15)
//            k         = s*64 + kc*32 + ((lane>>4)<<3) + j   (k' = kk*1024+d)
// ---------------------------------------------------------------------------
__global__ __launch_bounds__(256) void convert_all_kernel(
        const float* __restrict__ hidden, _Float16* __restrict__ hid16,
        const float* __restrict__ w1, const float* __restrict__ b2,
        _Float16* __restrict__ bfrag, float* __restrict__ logits,
        float* __restrict__ chunksum) {
    const int bx = blockIdx.x, b = blockIdx.y;
    const int tid = threadIdx.x;
    if (bx < NCHUNK) {
        const int d0 = tid * 4;
        const float* src = hidden + ((size_t)b * L_SZ + bx * 16) * D_SZ + d0;
        _Float16* dst = hid16 + ((size_t)b * L_SZ + bx * 16) * D_SZ + d0;
        float4 acc = make_float4(0.f, 0.f, 0.f, 0.f);
        #pragma unroll
        for (int r = 0; r < 16; ++r) {
            float4 v = *(const float4*)(src + (size_t)r * D_SZ);
            acc.x += v.x; acc.y += v.y; acc.z += v.z; acc.w += v.w;
            f16x4 o;
            o[0] = (_Float16)v.x; o[1] = (_Float16)v.y;
            o[2] = (_Float16)v.z; o[3] = (_Float16)v.w;
            *(f16x4*)(dst + (size_t)r * D_SZ) = o;
        }
        *(float4*)(chunksum + ((size_t)(b * NCHUNK + bx)) * D_SZ + d0) = acc;
    } else {
        int idx = (((bx - NCHUNK) * B_SZ) + b) * 256 + tid;   // bijective < 384*3072
        int j = idx & 7;
        int lane = (idx >> 3) & 63;
        int kc = (idx >> 9) & 1;
        int rest = idx >> 10;
        int s = rest % KSTEPS;
        int tt = rest / KSTEPS;
        int c = tt * 16 + (lane & 15);
        int k = s * 64 + kc * 32 + ((lane >> 4) << 3) + j;
        int kk = k >> 10, d = k & 1023;
        float v = (c < CH) ? w1[((size_t)c * 1024 + d) * 3 + kk] : 0.0f;
        bfrag[idx] = (_Float16)v;
        if (idx < B_SZ * LCONV) logits[idx] = b2[0];
    }
}

// ---------------------------------------------------------------------------
// fp16 MFMA conv GEMM, B-in-registers (R2 configuration — measured best at
// 57.8-60 us across R2/R3/R4/R7/R8/R9/R10; frozen at this empirical optimum).
// Tile 64 l x 192 c, BK=64, 4 waves (1x4), wave-tile 64x48 (4x3 of 16x16x32)
// -> 24 MFMAs per step per wave. B loaded per step straight into registers
// from fragment-ordered bfrag, prefetched one step ahead; A double-buffered
// in LDS via gl_lds16 (16 KB). Grid (2,32,8) = 512 blocks = 2/CU.
// Fused epilogue: relu(h+b1)*w2 reduced over c, atomicAdd into logits.
// ---------------------------------------------------------------------------
#define LDS_BUF 8192         // byte offset between the two A buffers

__global__ __launch_bounds__(256, 2) void conv_mfma_kernel(
        const _Float16* __restrict__ hid16, const _Float16* __restrict__ bfrag,
        const float* __restrict__ b1, const float* __restrict__ w2,
        float* __restrict__ logits) {
    const int nt = blockIdx.x;           // 0..1
    const int mt = blockIdx.y;           // 0..31
    const int b  = blockIdx.z;
    const int l0 = mt * 64;
    const int n0 = nt * 192;
    const int tid = threadIdx.x;
    const int wave = tid >> 6, lane = tid & 63;
    const int wn = wave;                 // 1x4 wave grid: wave = channel strip
    const int quad = lane >> 4, l16 = lane & 15;

    __shared__ __align__(16) char lds[2 * LDS_BUF];   // 16 KB: 2 x A 8K

    const _Float16* hb = hid16 + (size_t)b * L_SZ * D_SZ;

    // A staging source pointers: 512 entries (2 kc x 256), 2 per thread.
    // entry e (within kc): i=e>>6 (row block), m=i*16+(e&15), koff=((e>>4)&3)*8
    const _Float16* pa[2];
    #pragma unroll
    for (int p = 0; p < 2; ++p) {
        int f = p * 256 + tid;
        int kc = f >> 8, e = f & 255;
        int m = ((e >> 6) << 4) + (e & 15);
        int koff = ((e >> 4) & 3) * 8;
        int l = l0 + m; if (l > LCONV - 1) l = LCONV - 1;
        pa[p] = hb + (size_t)l * 1024 + kc * 32 + koff;
    }

    // B fragment pointers: one per jj, advancing 128 f16x8-units (2 KB) / step.
    // Fragment (tt, s, kc) lives at f16x8-unit index ((tt*48+s)*2+kc)*64 + lane.
    const f16x8* bp = (const f16x8*)bfrag;
    const f16x8* bptr[3];
    #pragma unroll
    for (int jj = 0; jj < 3; ++jj) {
        int tt = nt * 12 + wn * 3 + jj;
        bptr[jj] = bp + (size_t)tt * (KSTEPS * 2 * 64) + lane;
    }

    f32x4 acc[4][3] = {};
    f16x8 bc[3][2], bn[3][2];

    // ---- prologue: B step 0 into regs, A step 0 into buffer 0 ----
    #pragma unroll
    for (int jj = 0; jj < 3; ++jj)
        #pragma unroll
        for (int kc = 0; kc < 2; ++kc)
            bc[jj][kc] = bptr[jj][kc * 64];
    #pragma unroll
    for (int jj = 0; jj < 3; ++jj) bptr[jj] += 128;
    #pragma unroll
    for (int p = 0; p < 2; ++p)
        gl_lds16(pa[p], lds + (p * 256 + wave * 64) * 16);
    #pragma unroll
    for (int p = 0; p < 2; ++p) pa[p] += 64;
    __syncthreads();          // buffer 0 + bc ready

    int cur = 0;
    for (int s = 0; s < KSTEPS - 1; ++s) {
        const int nxt = cur ^ LDS_BUF;
        // prefetch B step s+1 into regs (consumed next iter; completes by barrier)
        #pragma unroll
        for (int jj = 0; jj < 3; ++jj)
            #pragma unroll
            for (int kc = 0; kc < 2; ++kc)
                bn[jj][kc] = bptr[jj][kc * 64];
        #pragma unroll
        for (int jj = 0; jj < 3; ++jj) bptr[jj] += 128;
        // prefetch A step s+1 into other LDS buffer
        #pragma unroll
        for (int p = 0; p < 2; ++p)
            gl_lds16(pa[p], lds + nxt + (p * 256 + wave * 64) * 16);
        #pragma unroll
        for (int p = 0; p < 2; ++p) pa[p] += 64;

        // compute step s from cur + bc
        #pragma unroll
        for (int kc = 0; kc < 2; ++kc) {
            f16x8 a[4];
            #pragma unroll
            for (int ii = 0; ii < 4; ++ii)
                a[ii] = *(const f16x8*)(lds + cur + (kc * 256 + ii * 64 + lane) * 16);
            #pragma unroll
            for (int ii = 0; ii < 4; ++ii)
                #pragma unroll
                for (int jj = 0; jj < 3; ++jj)
                    acc[ii][jj] = __builtin_amdgcn_mfma_f32_16x16x32_f16(
                        a[ii], bc[jj][kc], acc[ii][jj], 0, 0, 0);
        }
        __syncthreads();      // vmcnt(0): A nxt + B s+1 landed; cur reads done
        #pragma unroll
        for (int jj = 0; jj < 3; ++jj)
            #pragma unroll
            for (int kc = 0; kc < 2; ++kc)
                bc[jj][kc] = bn[jj][kc];
        cur = nxt;
    }
    // final step (no prefetch)
    #pragma unroll
    for (int kc = 0; kc < 2; ++kc) {
        f16x8 a[4];
        #pragma unroll
        for (int ii = 0; ii < 4; ++ii)
            a[ii] = *(const f16x8*)(lds + cur + (kc * 256 + ii * 64 + lane) * 16);
        #pragma unroll
        for (int ii = 0; ii < 4; ++ii)
            #pragma unroll
            for (int jj = 0; jj < 3; ++jj)
                acc[ii][jj] = __builtin_amdgcn_mfma_f32_16x16x32_f16(
                    a[ii], bc[jj][kc], acc[ii][jj], 0, 0, 0);
    }
    __syncthreads();          // before reusing lds as reduction scratch

    // --- epilogue: relu(acc + b1)*w2, reduce over c, atomic into logits ---
    float cb1[3], cw2[3];
    #pragma unroll
    for (int jj = 0; jj < 3; ++jj) {
        int ch = n0 + wn * 48 + jj * 16 + l16;
        bool v = ch < CH;
        cb1[jj] = v ? b1[ch] : 0.0f;
        cw2[jj] = v ? w2[ch] : 0.0f;
    }
    float* red = (float*)lds;   // [64][4]
    #pragma unroll
    for (int ii = 0; ii < 4; ++ii)
        #pragma unroll
        for (int r = 0; r < 4; ++r) {
            float P = 0.0f;
            #pragma unroll
            for (int jj = 0; jj < 3; ++jj) {
                float h = acc[ii][jj][r] + cb1[jj];
                if (h > 0.0f) P += h * cw2[jj];
            }
            P += __shfl_xor(P, 1);
            P += __shfl_xor(P, 2);
            P += __shfl_xor(P, 4);
            P += __shfl_xor(P, 8);
            if (l16 == 0)
                red[(ii * 16 + quad * 4 + r) * 4 + wn] = P;
        }
    __syncthreads();
    if (tid < 64) {
        int l = l0 + tid;
        if (l < LCONV)
            atomicAdd(&logits[b * LCONV + l],
                      red[tid * 4] + red[tid * 4 + 1] + red[tid * 4 + 2] + red[tid * 4 + 3]);
    }
}

// ---------------------------------------------------------------------------
// Fused fixup + boundary scan.
// Block b: stage logits[b] into LDS -> flag |v|<0.02 -> exact fp32 recompute
// of flagged in-LDS (expected ~0.4 flagged pipeline-wide) -> hard bits ->
// prefix scan -> segstart/short_mask -> per-batch (total,len) to scratch.
// (R11: chunk-prefix phase REMOVED — it was an 8-block serial walk; its
// output was only ever consumed as P[cL]-P[cF], so pool_gather now sums
// chunksum[cF..cL) directly with 4096-block parallelism instead.)
// ---------------------------------------------------------------------------
__global__ __launch_bounds__(256) void scanfix_kernel(
        const float* __restrict__ logits, const float* __restrict__ amask,
        const float* __restrict__ hidden, const float* __restrict__ w1,
        const float* __restrict__ b1, const float* __restrict__ w2,
        const float* __restrict__ b2,
        int* __restrict__ segstart, float* __restrict__ scratch,
        float* __restrict__ short_mask) {
    const int b = blockIdx.x, tid = threadIdx.x;
    __shared__ float slog[2048];
    __shared__ float hrow[3 * 1024];
    __shared__ int sdata[256];
    __shared__ float sred[256];
    __shared__ int flags[64];
    __shared__ int nflag;
    __shared__ int s_len, s_total;

    // stage logits into LDS
    for (int t = tid; t < LCONV; t += 256)
        slog[t] = logits[b * LCONV + t];
    if (tid == 0) nflag = 0;

    // len = sum(amask[b])
    int cnt = 0;
    #pragma unroll
    for (int j = 0; j < 8; ++j) {
        int l = tid * 8 + j;
        cnt += (amask[b * L_SZ + l] > 0.5f) ? 1 : 0;
    }
    sdata[tid] = cnt; __syncthreads();
    for (int off = 128; off > 0; off >>= 1) {
        if (tid < off) sdata[tid] += sdata[tid + off];
        __syncthreads();
    }
    if (tid == 0) s_len = sdata[0];
    __syncthreads();
    const int len = s_len;

    // ---- fixup phase: flag near-zero logits, recompute exactly in LDS ----
    for (int t = tid; t < LCONV; t += 256)
        if (fabsf(slog[t]) < 0.02f) {
            int k = atomicAdd(&nflag, 1);
            if (k < 64) flags[k] = t;
        }
    __syncthreads();
    const int nf = (nflag < 64) ? nflag : 64;
    for (int fi = 0; fi < nf; ++fi) {
        const int l = flags[fi];
        for (int t = tid; t < 3072; t += 256)
            hrow[t] = hidden[((size_t)b * L_SZ + l) * 1024 + t];
        __syncthreads();
        float tot = 0.0f;
        for (int c = tid; c < CH; c += 256) {
            const float* wr = w1 + (size_t)c * 3072;
            float dot = 0.0f;
            for (int d = 0; d < 1024; ++d)
                dot += hrow[d] * wr[d * 3] + hrow[1024 + d] * wr[d * 3 + 1]
                     + hrow[2048 + d] * wr[d * 3 + 2];
            float h = dot + b1[c];
            if (h > 0.0f) tot += h * w2[c];
        }
        sred[tid] = tot; __syncthreads();
        for (int off = 128; off > 0; off >>= 1) {
            if (tid < off) sred[tid] += sred[tid + off];
            __syncthreads();
        }
        if (tid == 0) slog[l] = sred[0] + b2[0];
        __syncthreads();
    }

    // ---- scan phase (bits from corrected LDS logits) ----
    int bits[8]; int tsum = 0;
    #pragma unroll
    for (int j = 0; j < 8; ++j) {
        int l = tid * 8 + j;
        int h = 0;
        if (l >= 2 && l < len) h = (slog[l - 2] > 0.0f) ? 1 : 0;
        if (len < L_SZ && l == len - 1) h = 1;
        bits[j] = h; tsum += h;
    }
    __syncthreads();
    sdata[tid] = tsum; __syncthreads();
    for (int off = 1; off < 256; off <<= 1) {
        int v = (tid >= off) ? sdata[tid - off] : 0;
        __syncthreads();
        sdata[tid] += v;
        __syncthreads();
    }
    const int texcl = sdata[tid] - tsum;
    if (tid == 255) s_total = sdata[255];
    __syncthreads();
    const int total = s_total;

    for (int s = tid; s <= NSEG; s += 256)
        segstart[b * (NSEG + 1) + s] = (s == 0) ? 0 : len;
    __syncthreads();
    int run = texcl;
    #pragma unroll
    for (int j = 0; j < 8; ++j) {
        int l = tid * 8 + j;
        if (bits[j]) {
            if (run + 1 <= NSEG) segstart[b * (NSEG + 1) + run + 1] = l + 1;
            run++;
        }
    }

    if (tid == 0) {
        scratch[b] = (float)total;       // summed by pool_gather (no memset)
        scratch[B_SZ + b] = (float)len;
    }
    for (int s = tid; s < NSEG; s += 256)
        short_mask[b * NSEG + s] = (s < total) ? 1.0f : 0.0f;
}

// ---------------------------------------------------------------------------
// Pool gather: sum[l0,l1) = sum of chunksum rows [cF, cL) (full chunks,
// L2-hot, 4-unrolled) + edge rows [l0, cF*16) and [cL*16, l1) from hidden.
// Same summation tree as R10's prefix-difference -> bit-identical output.
// Divide + sinusoidal PE fused; every element written -> no memset.
// Empty segment: a=0 -> 0*inv + PE. Block (0,0) finalizes nb/tp.
// ---------------------------------------------------------------------------
__global__ __launch_bounds__(256) void pool_gather_kernel(
        const float* __restrict__ hidden, const float* __restrict__ chunksum,
        const int* __restrict__ segstart, const float* __restrict__ scratch,
        float* __restrict__ pooled,
        float* __restrict__ out_nb, float* __restrict__ out_tp) {
    const int s = blockIdx.x, b = blockIdx.y, tid = threadIdx.x;
    if (s == 0 && b == 0 && tid == 0) {
        float nb = 0.f, tp = 0.f;
        #pragma unroll
        for (int i = 0; i < B_SZ; ++i) { nb += scratch[i]; tp += scratch[B_SZ + i]; }
        *out_nb = nb; *out_tp = tp;
    }
    const int l0 = segstart[b * (NSEG + 1) + s];
    const int l1 = segstart[b * (NSEG + 1) + s + 1];
    const int d0 = tid * 4;
    float4 a = make_float4(0.f, 0.f, 0.f, 0.f);
    if (l1 > l0) {
        const int cF = (l0 + 15) >> 4;   // first full chunk
        const int cL = l1 >> 4;          // end (exclusive) of full chunks
        const float* hb = hidden + (size_t)b * L_SZ * D_SZ + d0;
        if (cL > cF) {
            const float* cs = chunksum + ((size_t)b * NCHUNK) * D_SZ + d0;
            int c = cF;
            for (; c + 3 < cL; c += 4) {
                float4 v0 = *(const float4*)(cs + (size_t)c * D_SZ);
                float4 v1 = *(const float4*)(cs + (size_t)(c + 1) * D_SZ);
                float4 v2 = *(const float4*)(cs + (size_t)(c + 2) * D_SZ);
                float4 v3 = *(const float4*)(cs + (size_t)(c + 3) * D_SZ);
                a.x += v0.x + v1.x + v2.x + v3.x;
                a.y += v0.y + v1.y + v2.y + v3.y;
                a.z += v0.z + v1.z + v2.z + v3.z;
                a.w += v0.w + v1.w + v2.w + v3.w;
            }
            for (; c < cL; ++c) {
                float4 v = *(const float4*)(cs + (size_t)c * D_SZ);
                a.x += v.x; a.y += v.y; a.z += v.z; a.w += v.w;
            }
            for (int l = l0; l < cF * 16; ++l) {
                float4 v = *(const float4*)(hb + (size_t)l * D_SZ);
                a.x += v.x; a.y += v.y; a.z += v.z; a.w += v.w;
            }
            for (int l = cL * 16; l < l1; ++l) {
                float4 v = *(const float4*)(hb + (size_t)l * D_SZ);
                a.x += v.x; a.y += v.y; a.z += v.z; a.w += v.w;
            }
        } else {
            for (int l = l0; l < l1; ++l) {
                float4 v = *(const float4*)(hb + (size_t)l * D_SZ);
                a.x += v.x; a.y += v.y; a.z += v.z; a.w += v.w;
            }
        }
    }
    const float inv = 1.0f / ((float)(l1 - l0) + 1e-9f);
    const float ce = -9.210340371976184f / 512.0f;
    const int i = d0 >> 1;
    const float t0 = (float)s * expf(ce * (float)i);
    const float t1 = (float)s * expf(ce * (float)(i + 1));
    float4 out;
    out.x = a.x * inv + sinf(t0);
    out.y = a.y * inv + cosf(t0);
    out.z = a.z * inv + sinf(t1);
    out.w = a.w * inv + cosf(t1);
    *(float4*)(pooled + ((size_t)(b * NSEG + s)) * D_SZ + d0) = out;
}

// ---------------------------------------------------------------------------
extern "C" void kernel_launch(void* const* d_in, const int* in_sizes, int n_in,
                              void* d_out, int out_size, void* d_ws, size_t ws_size,
                              hipStream_t stream) {
    const float* hidden = (const float*)d_in[0];
    const float* amask  = (const float*)d_in[1];
    const float* w1     = (const float*)d_in[2];
    const float* b1     = (const float*)d_in[3];
    const float* w2     = (const float*)d_in[4];
    const float* b2     = (const float*)d_in[5];

    float* out    = (float*)d_out;
    float* pooled = out;
    float* nb     = out + POOLED_N;
    float* tp     = nb + 1;
    float* smask  = out + POOLED_N + 2;

    const size_t HID_E = (size_t)B_SZ * L_SZ * D_SZ;           // 16,777,216
    const size_t OFF_HID16    = 0;
    const size_t OFF_BPACK    = OFF_HID16 + HID_E * 2;                 // 32 MB
    const size_t OFF_LOGITS   = OFF_BPACK + (size_t)CP * KDIM * 2;     // +2.25 MB
    const size_t OFF_SEGSTART = OFF_LOGITS + (size_t)B_SZ * LCONV * 4;
    const size_t OFF_SCRATCH  = OFF_SEGSTART + (size_t)B_SZ * (NSEG + 1) * 4;
    const size_t OFF_CHUNKSUM = OFF_SCRATCH + 1024;

    _Float16* hid16   = (_Float16*)((char*)d_ws + OFF_HID16);
    _Float16* bfrag   = (_Float16*)((char*)d_ws + OFF_BPACK);
    float*    logits  = (float*)((char*)d_ws + OFF_LOGITS);
    int*      segst   = (int*)((char*)d_ws + OFF_SEGSTART);
    float*    scratch = (float*)((char*)d_ws + OFF_SCRATCH);
    float*    chsum   = (float*)((char*)d_ws + OFF_CHUNKSUM);

    convert_all_kernel<<<dim3(NCHUNK + W1XB, B_SZ), 256, 0, stream>>>(
        hidden, hid16, w1, b2, bfrag, logits, chsum);
    conv_mfma_kernel<<<dim3(2, 32, B_SZ), 256, 0, stream>>>(hid16, bfrag, b1, w2, logits);
    scanfix_kernel<<<B_SZ, 256, 0, stream>>>(logits, amask, hidden, w1, b1, w2, b2,
                                             segst, scratch, smask);
    pool_gather_kernel<<<dim3(NSEG, B_SZ), 256, 0, stream>>>(hidden, chsum, segst,
                                                             scratch, pooled, nb, tp);
}